// Round 6
// baseline (1123.614 us; speedup 1.0000x reference)
//
#include <hip/hip_runtime.h>

#define N_NODES 100000
#define N1 (N_NODES + 1)
#define N_EDGES 3200000
#define N_GRAPHS 1000
#define IN_DIM 10
#define HIDDEN 64
#define NQUADS (N_NODES / 4)  // 25000, exact

#define NRANGES 8
#define RANGE_SIZE ((N_NODES + NRANGES - 1) / NRANGES)
#define CHUNK_EDGES 4096
#define LAYER_BLOCKS 2048

typedef float f32x4 __attribute__((ext_vector_type(4)));

// ---------------- degree histogram ----------------
__global__ void k_deg(const int* __restrict__ col, int* __restrict__ deg) {
    int e = blockIdx.x * blockDim.x + threadIdx.x;
    if (e < N_EDGES) atomicAdd(&deg[col[e]], 1);
}

// ---------------- hierarchical exclusive scan (offsets) ----------------
__global__ __launch_bounds__(1024) void k_scan_block(const int* __restrict__ deg,
                                                     int* __restrict__ offs,
                                                     int* __restrict__ bsums) {
    __shared__ int s[1024];
    int t = threadIdx.x;
    int i = blockIdx.x * 1024 + t;
    int v = (i < N_NODES) ? deg[i] : 0;
    s[t] = v;
    __syncthreads();
    for (int d = 1; d < 1024; d <<= 1) {
        int x = (t >= d) ? s[t - d] : 0;
        __syncthreads();
        s[t] += x;
        __syncthreads();
    }
    if (i < N_NODES) offs[i] = s[t] - v;
    if (t == 1023) bsums[blockIdx.x] = s[t];
}

__global__ __launch_bounds__(128) void k_scan_top(int* __restrict__ bsums, int nb) {
    __shared__ int s[128];
    int t = threadIdx.x;
    int v = (t < nb) ? bsums[t] : 0;
    s[t] = v;
    __syncthreads();
    for (int d = 1; d < 128; d <<= 1) {
        int x = (t >= d) ? s[t - d] : 0;
        __syncthreads();
        s[t] += x;
        __syncthreads();
    }
    if (t < nb) bsums[t] = s[t] - v;
}

__global__ __launch_bounds__(1024) void k_scan_add(int* __restrict__ offs,
                                                   const int* __restrict__ bsums) {
    int i = blockIdx.x * 1024 + threadIdx.x;
    if (i < N_NODES) offs[i] += bsums[blockIdx.x];
}

// ---------------- dinv ----------------
__global__ void k_dinv(const int* __restrict__ deg, float* __restrict__ dinv) {
    int n = blockIdx.x * blockDim.x + threadIdx.x;
    if (n < N_NODES) {
        int d = deg[n];
        dinv[n] = (d > 0) ? rsqrtf((float)d) : 0.f;
    }
}

// ---------------- CSR fill, XCD-range-partitioned (R2, kept) ----------------
__global__ __launch_bounds__(256) void k_fill(const int* __restrict__ row,
                                              const int* __restrict__ col,
                                              const int* __restrict__ offs,
                                              int* __restrict__ cursor,
                                              int* __restrict__ csr_src) {
    int range = blockIdx.x & (NRANGES - 1);
    int chunk = blockIdx.x >> 3;
    int lo = range * RANGE_SIZE;
    int hi = lo + RANGE_SIZE;
    int base = chunk * CHUNK_EDGES + threadIdx.x;
#pragma unroll
    for (int k = 0; k < CHUNK_EDGES / 256; ++k) {
        int e = base + k * 256;
        if (e < N_EDGES) {
            int c = col[e];
            int r = row[e];
            if (c >= lo && c < hi) {
                int p = atomicAdd(&cursor[c], 1);
                csr_src[offs[c] + p] = r;
            }
        }
    }
}

// ---------------- degree counting-sort: hist -> scan -> place ----------------
__global__ void k_hist(const int* __restrict__ deg, int* __restrict__ hist) {
    int n = blockIdx.x * blockDim.x + threadIdx.x;
    if (n < N_NODES) atomicAdd(&hist[min(deg[n], 255)], 1);
}

__global__ __launch_bounds__(256) void k_hscan(int* __restrict__ hist, int* __restrict__ cur) {
    __shared__ int s[256];
    int t = threadIdx.x;
    int v = hist[t];
    s[t] = v;
    __syncthreads();
    for (int d = 1; d < 256; d <<= 1) {
        int x = (t >= d) ? s[t - d] : 0;
        __syncthreads();
        s[t] += x;
        __syncthreads();
    }
    cur[t] = s[t] - v;  // exclusive scan -> absolute cursor per bin
}

__global__ void k_place(const int* __restrict__ deg, int* __restrict__ cur,
                        int* __restrict__ sorted) {
    int n = blockIdx.x * blockDim.x + threadIdx.x;
    if (n < N_NODES) {
        int b = min(deg[n], 255);
        int p = atomicAdd(&cur[b], 1);
        sorted[p] = n;
    }
}

// ---------------- prescale x into padded 16-float rows [N1][16] ----------------
__global__ void k_prex(const float* __restrict__ x, const float* __restrict__ dinv,
                       float* __restrict__ xs) {
    int i = blockIdx.x * blockDim.x + threadIdx.x;
    if (i >= N1 * 16) return;
    int n = i >> 4, d = i & 15;
    float v = 0.f;
    if (n < N_NODES && d < IN_DIM) v = x[n * IN_DIM + d] * dinv[n];
    xs[i] = v;
}

// ---------------- graph boundaries (batch is sorted) ----------------
__global__ void k_bounds(const int* __restrict__ batch, int* __restrict__ gmin,
                         int* __restrict__ gmax) {
    int n = blockIdx.x * blockDim.x + threadIdx.x;
    if (n < N_NODES) {
        int g = batch[n];
        atomicMin(&gmin[g], n);
        atomicMax(&gmax[g], n + 1);
    }
}

// ================= layer 1: 16-dim rows, 4 lanes/row (16 rows per load) =================
// hout[n] = relu((sum_src xs[src]) * dinv[n] @ W1 + b1) * dinv[n]
__global__ __launch_bounds__(256) void k_conv16(const float* __restrict__ xs,
                                                const float* __restrict__ dinv,
                                                const int* __restrict__ offs,
                                                const int* __restrict__ deg,
                                                const int* __restrict__ csr,
                                                const int* __restrict__ sorted,
                                                const float* __restrict__ W1,
                                                const float* __restrict__ b1,
                                                float* __restrict__ hout) {
    __shared__ f32x4 sW1[16][16];
    {
        int i = threadIdx.x;  // 256 = 16*16 exactly
        int k = i >> 4, ff = i & 15;
        f32x4 z = {0.f, 0.f, 0.f, 0.f};
        sW1[k][ff] = (k < IN_DIM) ? *(const f32x4*)&W1[k * HIDDEN + ff * 4] : z;
    }
    __syncthreads();
    int lane = threadIdx.x & 63;
    int f = lane & 15;          // index within 16-lane group
    int gbase = lane & 48;      // group base lane
    int sub = (lane >> 2) & 3;  // edge subslot
    int c = lane & 3;           // float4 column in 16-dim row
    f32x4 b4 = *(const f32x4*)&b1[f * 4];

    int wid = (blockIdx.x * 256 + threadIdx.x) >> 6;
    int nwaves = gridDim.x * 4;
    for (int quad = wid; quad < NQUADS; quad += nwaves) {
        int n = sorted[quad * 4 + (lane >> 4)];
        int start = offs[n], dn = deg[n];
        float di = dinv[n];
        int m1 = max(dn, __shfl_xor(dn, 16));
        int dnw = max(m1, __shfl_xor(m1, 32));
        f32x4 acc = {0.f, 0.f, 0.f, 0.f};
        for (int base = 0; base < dnw; base += 16) {
            int sv = __builtin_nontemporal_load(&csr[start + base + f]);
            sv = (base + f < dn) ? sv : N_NODES;
            int sj0 = __shfl(sv, gbase + 0 + sub);
            int sj1 = __shfl(sv, gbase + 4 + sub);
            int sj2 = __shfl(sv, gbase + 8 + sub);
            int sj3 = __shfl(sv, gbase + 12 + sub);
            f32x4 v0 = *(const f32x4*)&xs[(size_t)sj0 * 16 + c * 4];
            f32x4 v1 = *(const f32x4*)&xs[(size_t)sj1 * 16 + c * 4];
            f32x4 v2 = *(const f32x4*)&xs[(size_t)sj2 * 16 + c * 4];
            f32x4 v3 = *(const f32x4*)&xs[(size_t)sj3 * 16 + c * 4];
            acc += v0 + v1 + v2 + v3;
        }
        // reduce over the 4 edge subslots (lanes c, c+4, c+8, c+12 within group)
        f32x4 r;
        r.x = __shfl_xor(acc.x, 4); r.y = __shfl_xor(acc.y, 4);
        r.z = __shfl_xor(acc.z, 4); r.w = __shfl_xor(acc.w, 4);
        acc += r;
        r.x = __shfl_xor(acc.x, 8); r.y = __shfl_xor(acc.y, 8);
        r.z = __shfl_xor(acc.z, 8); r.w = __shfl_xor(acc.w, 8);
        acc += r;
        acc *= di;
        // dense: out dims f*4..f*4+3; a_k at lane gbase+(k>>2), component k&3
        f32x4 out = b4;
#pragma unroll
        for (int k = 0; k < 16; ++k) {
            float srcv = (k & 3) == 0 ? acc.x : (k & 3) == 1 ? acc.y : (k & 3) == 2 ? acc.z : acc.w;
            float ak = __shfl(srcv, gbase + (k >> 2));
            f32x4 w4 = sW1[k][f];
            out += ak * w4;
        }
        out.x = fmaxf(out.x, 0.f) * di;
        out.y = fmaxf(out.y, 0.f) * di;
        out.z = fmaxf(out.z, 0.f) * di;
        out.w = fmaxf(out.w, 0.f) * di;
        __builtin_nontemporal_store(out, (f32x4*)&hout[(size_t)n * HIDDEN + f * 4]);
    }
}

// ================= wide conv: 64-dim rows, 16 lanes/row (4 rows per load) =================
// DENSE=1: hout[n] = relu(agg*di @ W + b) * di   (layers 2)
// DENSE=0: hout[n] = agg*di                       (layer 3, pre-pool)
template <int DENSE>
__global__ __launch_bounds__(256) void k_conv64(const float* __restrict__ hs,
                                                const float* __restrict__ dinv,
                                                const int* __restrict__ offs,
                                                const int* __restrict__ deg,
                                                const int* __restrict__ csr,
                                                const int* __restrict__ sorted,
                                                const float* __restrict__ W,
                                                const float* __restrict__ b,
                                                float* __restrict__ hout) {
    __shared__ f32x4 sW4[HIDDEN][16];
    if (DENSE) {
        for (int i = threadIdx.x; i < HIDDEN * 16; i += 256) {
            int k = i >> 4, ff = i & 15;
            sW4[k][ff] = *(const f32x4*)&W[k * HIDDEN + ff * 4];
        }
        __syncthreads();
    }
    int lane = threadIdx.x & 63;
    int f = lane & 15;
    int gbase = lane & 48;
    f32x4 b4 = {0.f, 0.f, 0.f, 0.f};
    if (DENSE) b4 = *(const f32x4*)&b[f * 4];

    int wid = (blockIdx.x * 256 + threadIdx.x) >> 6;
    int nwaves = gridDim.x * 4;
    for (int quad = wid; quad < NQUADS; quad += nwaves) {
        int n = sorted[quad * 4 + (lane >> 4)];
        int start = offs[n], dn = deg[n];
        float di = dinv[n];
        int m1 = max(dn, __shfl_xor(dn, 16));
        int dnw = max(m1, __shfl_xor(m1, 32));
        f32x4 acc = {0.f, 0.f, 0.f, 0.f};
        for (int base = 0; base < dnw; base += 16) {
            int sv = __builtin_nontemporal_load(&csr[start + base + f]);
            sv = (base + f < dn) ? sv : N_NODES;
#pragma unroll
            for (int jj = 0; jj < 2; ++jj) {
                f32x4 v[8];
#pragma unroll
                for (int j = 0; j < 8; ++j) {
                    int sj = __shfl(sv, gbase + jj * 8 + j);
                    v[j] = *(const f32x4*)&hs[(size_t)sj * HIDDEN + f * 4];
                }
#pragma unroll
                for (int j = 0; j < 8; ++j) acc += v[j];
            }
        }
        acc *= di;
        f32x4 out;
        if (DENSE) {
            out = b4;
#pragma unroll
            for (int k = 0; k < HIDDEN; ++k) {
                float srcv = (k & 3) == 0 ? acc.x : (k & 3) == 1 ? acc.y : (k & 3) == 2 ? acc.z : acc.w;
                float ak = __shfl(srcv, gbase + (k >> 2));
                f32x4 w4 = sW4[k][f];
                out += ak * w4;
            }
            out.x = fmaxf(out.x, 0.f) * di;
            out.y = fmaxf(out.y, 0.f) * di;
            out.z = fmaxf(out.z, 0.f) * di;
            out.w = fmaxf(out.w, 0.f) * di;
        } else {
            out = acc;
        }
        __builtin_nontemporal_store(out, (f32x4*)&hout[(size_t)n * HIDDEN + f * 4]);
    }
}

// ================= pool: gpool[g][d] = sum_{n in [gmin,gmax)} agg[n][d]; no atomics ========
__global__ __launch_bounds__(64) void k_pool(const float* __restrict__ agg,
                                             const int* __restrict__ gmin,
                                             const int* __restrict__ gmax,
                                             float* __restrict__ gpool,
                                             int* __restrict__ gcnt) {
    int g = blockIdx.x;
    int d = threadIdx.x;
    int lo = gmin[g], hi = gmax[g];
    float s = 0.f;
    for (int n = lo; n < hi; ++n) s += agg[(size_t)n * HIDDEN + d];
    gpool[g * HIDDEN + d] = s;
    if (d == 0) gcnt[g] = (hi > lo) ? (hi - lo) : 0;
}

// ---------------- final: pooled @ W3 + cnt*b3, @ Wl + bl, softmax ----------------
__global__ __launch_bounds__(256) void k_final(const float* __restrict__ gpool,
                                               const int* __restrict__ gcnt,
                                               const float* __restrict__ W3,
                                               const float* __restrict__ b3,
                                               const float* __restrict__ Wl,
                                               const float* __restrict__ bl,
                                               float* __restrict__ out) {
    int wid = (blockIdx.x * blockDim.x + threadIdx.x) >> 6;
    int lane = threadIdx.x & 63;
    if (wid >= N_GRAPHS) return;
    float pre = gpool[wid * HIDDEN + lane];
    float cnt = (float)gcnt[wid];
    float emb = cnt * b3[lane];
    for (int k = 0; k < HIDDEN; ++k) {
        emb += __shfl(pre, k) * W3[k * HIDDEN + lane];
    }
    float p0 = emb * Wl[lane * 2 + 0];
    float p1 = emb * Wl[lane * 2 + 1];
    for (int d = 32; d > 0; d >>= 1) {
        p0 += __shfl_xor(p0, d);
        p1 += __shfl_xor(p1, d);
    }
    if (lane == 0) {
        float l0 = p0 + bl[0], l1 = p1 + bl[1];
        float m = fmaxf(l0, l1);
        float e0 = __expf(l0 - m), e1 = __expf(l1 - m);
        float inv = 1.f / (e0 + e1);
        out[wid * 2 + 0] = e0 * inv;
        out[wid * 2 + 1] = e1 * inv;
    }
}

extern "C" void kernel_launch(void* const* d_in, const int* in_sizes, int n_in,
                              void* d_out, int out_size, void* d_ws, size_t ws_size,
                              hipStream_t stream) {
    const float* x = (const float*)d_in[0];
    const int* edge = (const int*)d_in[1];
    const int* batch = (const int*)d_in[2];
    const float* W1 = (const float*)d_in[3];
    const float* b1 = (const float*)d_in[4];
    const float* W2 = (const float*)d_in[5];
    const float* b2 = (const float*)d_in[6];
    const float* W3 = (const float*)d_in[7];
    const float* b3 = (const float*)d_in[8];
    const float* Wl = (const float*)d_in[9];
    const float* bl = (const float*)d_in[10];
    float* out = (float*)d_out;

    const int* row = edge;
    const int* col = edge + N_EDGES;

    char* ws = (char*)d_ws;
    size_t off = 0;
    auto alloc = [&](size_t bytes) -> void* {
        void* p = ws + off;
        off = (off + bytes + 255) & ~(size_t)255;
        return p;
    };
    int* deg = (int*)alloc((size_t)N_NODES * 4);
    int* offs = (int*)alloc((size_t)N_NODES * 4);
    int* bsums = (int*)alloc(128 * 4);
    int* cursor = (int*)alloc((size_t)N_NODES * 4);
    float* dinv = (float*)alloc((size_t)N_NODES * 4);
    int* sorted = (int*)alloc((size_t)N_NODES * 4);
    int* hist = (int*)alloc(256 * 4);
    int* bincur = (int*)alloc(256 * 4);
    int* csr_src = (int*)alloc(((size_t)N_EDGES + 1024) * 4);
    float* xs = (float*)alloc((size_t)N1 * 16 * 4);        // [N1][16], x*dinv, padded
    float* h1 = (float*)alloc((size_t)N1 * HIDDEN * 4);    // h1*dinv; later reused as agg3
    float* h2 = (float*)alloc((size_t)N1 * HIDDEN * 4);    // h2*dinv
    float* gpool = (float*)alloc((size_t)N_GRAPHS * HIDDEN * 4);
    int* gmin = (int*)alloc((size_t)N_GRAPHS * 4);
    int* gmax = (int*)alloc((size_t)N_GRAPHS * 4);
    int* gcnt = (int*)alloc((size_t)N_GRAPHS * 4);

    hipMemsetAsync(deg, 0, (size_t)N_NODES * 4, stream);
    hipMemsetAsync(cursor, 0, (size_t)N_NODES * 4, stream);
    hipMemsetAsync(hist, 0, 256 * 4, stream);
    hipMemsetAsync(gmin, 0x7f, (size_t)N_GRAPHS * 4, stream);
    hipMemsetAsync(gmax, 0, (size_t)N_GRAPHS * 4, stream);
    // zero the gather-sink rows (row N_NODES)
    hipMemsetAsync(h1 + (size_t)N_NODES * HIDDEN, 0, HIDDEN * 4, stream);
    hipMemsetAsync(h2 + (size_t)N_NODES * HIDDEN, 0, HIDDEN * 4, stream);

    const int EB = (N_EDGES + 255) / 256;
    const int NB1024 = (N_NODES + 1023) / 1024;
    const int NB256 = (N_NODES + 255) / 256;

    k_deg<<<EB, 256, 0, stream>>>(col, deg);
    k_scan_block<<<NB1024, 1024, 0, stream>>>(deg, offs, bsums);
    k_scan_top<<<1, 128, 0, stream>>>(bsums, NB1024);
    k_scan_add<<<NB1024, 1024, 0, stream>>>(offs, bsums);
    k_dinv<<<NB256, 256, 0, stream>>>(deg, dinv);

    // degree counting-sort (equalizes quad degrees -> no maxd waste, balanced waves)
    k_hist<<<NB256, 256, 0, stream>>>(deg, hist);
    k_hscan<<<1, 256, 0, stream>>>(hist, bincur);
    k_place<<<NB256, 256, 0, stream>>>(deg, bincur, sorted);

    const int NCHUNKS = (N_EDGES + CHUNK_EDGES - 1) / CHUNK_EDGES;
    k_fill<<<NCHUNKS * NRANGES, 256, 0, stream>>>(row, col, offs, cursor, csr_src);
    k_prex<<<(N1 * 16 + 255) / 256, 256, 0, stream>>>(x, dinv, xs);
    k_bounds<<<NB256, 256, 0, stream>>>(batch, gmin, gmax);

    k_conv16<<<LAYER_BLOCKS, 256, 0, stream>>>(xs, dinv, offs, deg, csr_src, sorted, W1, b1, h1);
    k_conv64<1><<<LAYER_BLOCKS, 256, 0, stream>>>(h1, dinv, offs, deg, csr_src, sorted, W2, b2, h2);
    k_conv64<0><<<LAYER_BLOCKS, 256, 0, stream>>>(h2, dinv, offs, deg, csr_src, sorted, W2, b2, h1);
    k_pool<<<N_GRAPHS, 64, 0, stream>>>(h1, gmin, gmax, gpool, gcnt);
    k_final<<<(N_GRAPHS * 64 + 255) / 256, 256, 0, stream>>>(gpool, gcnt, W3, b3, Wl, bl, out);
}